// Round 1
// baseline (26.509 us; speedup 1.0000x reference)
//
#include <hip/hip_runtime.h>
#include <math.h>

// Tropical (max-times) matmul: out[i,k] = max_j sigmoid(A[j,k]) * x[i,j]
// x: [2048, 256] f32   A: [256, 512] f32   out: [2048, 512] f32
//
// Compute-bound on the vector ALU (no fp32 MFMA on CDNA4; max-reduce can't
// use matrix cores anyway). 64x64 output tile per block, 4x4 per thread,
// grid = 32*8 = 256 blocks = 1 per CU. J staged in 4 chunks of 64 with
// register prefetch; x stored transposed in LDS (padded stride 68 words:
// 16B-aligned b128 reads, conflict-reduced transpose writes).

constexpr int BATCH = 2048;
constexpr int JDIM  = 256;
constexpr int KDIM  = 512;

constexpr int BI  = 64;          // rows per block
constexpr int BK  = 64;          // cols per block
constexpr int JC  = 64;          // j-chunk staged in LDS
constexpr int NCH = JDIM / JC;   // 4 chunks
constexpr int PAD = 68;          // LDS row stride (words); 68*4=272B, 16B-aligned

__device__ __forceinline__ float sigmoidf_fast(float a) {
    return 1.0f / (1.0f + __expf(-a));
}

__global__ __launch_bounds__(256) void tropical_mm_kernel(
        const float* __restrict__ x,
        const float* __restrict__ A,
        float* __restrict__ out) {
    __shared__ float xT[JC][PAD];   // [j_local][i_local]  (transposed x tile)
    __shared__ float Wt[JC][PAD];   // [j_local][k_local]  (sigmoid(A) tile)

    const int tid = threadIdx.x;
    const int tx  = tid & 15;       // 16 -> k direction (4 cols each)
    const int ty  = tid >> 4;       // 16 -> i direction (4 rows each)
    const int bk  = blockIdx.x & 7;   // 8 k-tiles
    const int bi  = blockIdx.x >> 3;  // 32 i-tiles
    const int i0  = bi * BI;
    const int k0  = bk * BK;

    // -------- register prefetch buffers (one J-chunk) --------
    // per pass p: x[i0 + p*16 + ty][jb + tx*4 .. +3]   (4 consecutive j)
    //             A[jb + p*16 + ty][k0 + tx*4 .. +3]   (4 consecutive k)
    float4 px[4], pa[4];

    {
        const int jb = 0;
        #pragma unroll
        for (int p = 0; p < 4; ++p) {
            const int iL = p * 16 + ty;
            const int jL = p * 16 + ty;
            px[p] = *(const float4*)&x[(i0 + iL) * JDIM + jb + tx * 4];
            pa[p] = *(const float4*)&A[(jb + jL) * KDIM + k0 + tx * 4];
        }
    }

    float acc[4][4];
    #pragma unroll
    for (int a = 0; a < 4; ++a)
        #pragma unroll
        for (int b = 0; b < 4; ++b)
            acc[a][b] = -__builtin_inff();

    const int ty4 = ty * 4;
    const int tx4 = tx * 4;

    for (int c = 0; c < NCH; ++c) {
        __syncthreads();   // previous compute done before overwriting LDS

        // -------- store prefetched chunk to LDS --------
        #pragma unroll
        for (int p = 0; p < 4; ++p) {
            const int iL = p * 16 + ty;
            // transpose x: px[p] holds 4 consecutive j at fixed i
            xT[tx4 + 0][iL] = px[p].x;
            xT[tx4 + 1][iL] = px[p].y;
            xT[tx4 + 2][iL] = px[p].z;
            xT[tx4 + 3][iL] = px[p].w;

            const int jL = p * 16 + ty;
            float4 w;
            w.x = sigmoidf_fast(pa[p].x);
            w.y = sigmoidf_fast(pa[p].y);
            w.z = sigmoidf_fast(pa[p].z);
            w.w = sigmoidf_fast(pa[p].w);
            *(float4*)&Wt[jL][tx4] = w;
        }
        __syncthreads();

        // -------- issue global loads for next chunk (hidden under compute) --------
        if (c + 1 < NCH) {
            const int jb = (c + 1) * JC;
            #pragma unroll
            for (int p = 0; p < 4; ++p) {
                const int iL = p * 16 + ty;
                const int jL = p * 16 + ty;
                px[p] = *(const float4*)&x[(i0 + iL) * JDIM + jb + tx * 4];
                pa[p] = *(const float4*)&A[(jb + jL) * KDIM + k0 + tx * 4];
            }
        }

        // -------- compute: 64 j, 2 at a time, v_max3 fusion --------
        #pragma unroll 4
        for (int j = 0; j < JC; j += 2) {
            const float4 xv0 = *(const float4*)&xT[j][ty4];
            const float4 wv0 = *(const float4*)&Wt[j][tx4];
            const float4 xv1 = *(const float4*)&xT[j + 1][ty4];
            const float4 wv1 = *(const float4*)&Wt[j + 1][tx4];
            const float x0[4] = {xv0.x, xv0.y, xv0.z, xv0.w};
            const float w0[4] = {wv0.x, wv0.y, wv0.z, wv0.w};
            const float x1[4] = {xv1.x, xv1.y, xv1.z, xv1.w};
            const float w1[4] = {wv1.x, wv1.y, wv1.z, wv1.w};
            #pragma unroll
            for (int a = 0; a < 4; ++a)
                #pragma unroll
                for (int b = 0; b < 4; ++b)
                    // fmaxf(fmaxf(p0,p1),acc) -> v_max3_f32
                    acc[a][b] = fmaxf(fmaxf(x0[a] * w0[b], x1[a] * w1[b]), acc[a][b]);
        }
    }

    // -------- write output --------
    #pragma unroll
    for (int a = 0; a < 4; ++a) {
        float4 o;
        o.x = acc[a][0];
        o.y = acc[a][1];
        o.z = acc[a][2];
        o.w = acc[a][3];
        *(float4*)&out[(i0 + ty4 + a) * KDIM + k0 + tx4] = o;
    }
}

extern "C" void kernel_launch(void* const* d_in, const int* in_sizes, int n_in,
                              void* d_out, int out_size, void* d_ws, size_t ws_size,
                              hipStream_t stream) {
    const float* x = (const float*)d_in[0];
    const float* A = (const float*)d_in[1];
    float* out = (float*)d_out;

    dim3 grid(256);   // 32 i-tiles * 8 k-tiles, 1 block per CU
    dim3 block(256);
    hipLaunchKernelGGL(tropical_mm_kernel, grid, block, 0, stream, x, A, out);
}